// Round 3
// baseline (296.058 us; speedup 1.0000x reference)
//
#include <hip/hip_runtime.h>
#include <hip/hip_bf16.h>

#define LOG2E 1.4426950408889634f

typedef __attribute__((ext_vector_type(8))) short frag_ab;   // 8 bf16 (4 VGPRs)
typedef __attribute__((ext_vector_type(4))) float frag_cd;   // 4 fp32 acc

// fp32 -> bf16 bits, round-to-nearest-even (inputs finite)
__device__ inline short f2bf(float f) {
    union { float f; unsigned u; } v; v.f = f;
    unsigned r = v.u + 0x7fffu + ((v.u >> 16) & 1u);
    return (short)(r >> 16);
}

// Blocks 0..63: convert W[128][1024] fp32 -> wbf bf16 in MFMA *fragment order*:
//   element (h,k): chunk c=k>>6, kstep s=(k>>5)&1, kg=(k>>3)&3, j=k&7,
//   ntile nt=h>>4, m=h&15, lane=kg*16+m
//   wbf[ (((c*8+nt)*2+s)*64 + lane)*8 + j ]
// Blocks 64..191: rmm[h] = log2e*max_k cov[h,:], rmm[128+h] = log2e*min_k.
__global__ __launch_bounds__(256) void prep_kernel(const float* __restrict__ W,
                                                   const float* __restrict__ cov,
                                                   short* __restrict__ wbf,
                                                   float* __restrict__ rmm) {
    if (blockIdx.x < 64) {
        int g = blockIdx.x * 256 + threadIdx.x;   // 0..16383
        int h = g >> 7;
        int k0 = (g & 127) << 3;
        const float* src = W + h * 1024 + k0;
        float4 w0 = *(const float4*)src;
        float4 w1 = *(const float4*)(src + 4);
        frag_ab af;
        af[0] = f2bf(w0.x); af[1] = f2bf(w0.y); af[2] = f2bf(w0.z); af[3] = f2bf(w0.w);
        af[4] = f2bf(w1.x); af[5] = f2bf(w1.y); af[6] = f2bf(w1.z); af[7] = f2bf(w1.w);
        int c = k0 >> 6, s = (k0 >> 5) & 1, kg = (k0 >> 3) & 3;
        int nt = h >> 4, m = h & 15, lane = kg * 16 + m;
        int dst = (((c * 8 + nt) * 2 + s) * 64 + lane) * 8;
        *(frag_ab*)(wbf + dst) = af;
    } else {
        int h = blockIdx.x - 64;
        int lane = threadIdx.x;
        if (lane < 64) {
            float c1 = cov[h * 128 + lane];
            float c2 = cov[h * 128 + 64 + lane];
            float mx = fmaxf(c1, c2), mn = fminf(c1, c2);
            for (int o = 1; o < 64; o <<= 1) {
                mx = fmaxf(mx, __shfl_xor(mx, o, 64));
                mn = fminf(mn, __shfl_xor(mn, o, 64));
            }
            if (lane == 0) { rmm[h] = LOG2E * mx; rmm[128 + h] = LOG2E * mn; }
        }
    }
}

// vm[row][h] = sum_k x[row][k]*W[h][k].
// Barrier-free: each wave owns 16 rows x 128 h independently. B fragments are
// read directly from wbf (fragment-ordered, L1/L2-hot, 1KB coalesced per
// instruction) into a 16-frag register array (16 outstanding loads / chunk).
// A (x) prefetched one 64-k chunk ahead; every x byte read exactly once.
__global__ __launch_bounds__(256) void proj_kernel(const float* __restrict__ x,
                                                   const short* __restrict__ wbf,
                                                   float* __restrict__ vm) {
    const int tid = threadIdx.x;
    const int lane = tid & 63;
    const int wave = tid >> 6;
    const int m = lane & 15, kg = lane >> 4;
    const long rowbase = ((long)blockIdx.x * 4 + wave) * 16;
    const float* xrow = x + (rowbase + m) * 1024 + kg * 8;
    const char* wb = (const char*)wbf + lane * 16;

    frag_cd acc[8];
#pragma unroll
    for (int nt = 0; nt < 8; ++nt) acc[nt] = (frag_cd){0.f, 0.f, 0.f, 0.f};

    // prefetch A chunk 0
    float4 a0 = *(const float4*)(xrow);
    float4 a1 = *(const float4*)(xrow + 4);
    float4 a2 = *(const float4*)(xrow + 32);
    float4 a3 = *(const float4*)(xrow + 36);

    for (int c = 0; c < 16; ++c) {
        // issue all 16 B-fragment loads for this chunk (fills the MLP window)
        frag_ab bfr[16];
        const char* bc = wb + c * 16384;
#pragma unroll
        for (int f = 0; f < 16; ++f)
            bfr[f] = *(const frag_ab*)(bc + f * 1024);

        // prefetch next A chunk
        float4 n0, n1, n2, n3;
        if (c < 15) {
            const float* xn = xrow + (c + 1) * 64;
            n0 = *(const float4*)(xn);
            n1 = *(const float4*)(xn + 4);
            n2 = *(const float4*)(xn + 32);
            n3 = *(const float4*)(xn + 36);
        }

        frag_ab af0, af1;
        af0[0] = f2bf(a0.x); af0[1] = f2bf(a0.y); af0[2] = f2bf(a0.z); af0[3] = f2bf(a0.w);
        af0[4] = f2bf(a1.x); af0[5] = f2bf(a1.y); af0[6] = f2bf(a1.z); af0[7] = f2bf(a1.w);
        af1[0] = f2bf(a2.x); af1[1] = f2bf(a2.y); af1[2] = f2bf(a2.z); af1[3] = f2bf(a2.w);
        af1[4] = f2bf(a3.x); af1[5] = f2bf(a3.y); af1[6] = f2bf(a3.z); af1[7] = f2bf(a3.w);

#pragma unroll
        for (int nt = 0; nt < 8; ++nt) {
            acc[nt] = __builtin_amdgcn_mfma_f32_16x16x32_bf16(af0, bfr[nt * 2 + 0], acc[nt], 0, 0, 0);
            acc[nt] = __builtin_amdgcn_mfma_f32_16x16x32_bf16(af1, bfr[nt * 2 + 1], acc[nt], 0, 0, 0);
        }
        if (c < 15) { a0 = n0; a1 = n1; a2 = n2; a3 = n3; }
    }

    // C/D: col = lane&15 (=h within tile), row = kg*4 + r
#pragma unroll
    for (int nt = 0; nt < 8; ++nt) {
#pragma unroll
        for (int r = 0; r < 4; ++r) {
            long row = rowbase + kg * 4 + r;
            vm[row * 128 + nt * 16 + m] = acc[nt][r];
        }
    }
}

// out[b,k] = bias[k] + sum_h (v[b,h]/l[b,h]) * exp2(mask[b,h]*cov2[h,k] - m2[b,h])
// 512 threads: thread (i=t>>4, j=t&15) owns h in [4i,4i+4), k in [8j,8j+8).
// k-reduction (l) via 16-lane shfl butterfly (no LDS, no barrier);
// h-reduction via obuf LDS. 2 barriers per b.
__global__ __launch_bounds__(512, 4) void combine_kernel(const float* __restrict__ vm,
                                                         const float* __restrict__ cov,
                                                         const float* __restrict__ bias,
                                                         const float* __restrict__ rmm,
                                                         float* __restrict__ out, int B) {
    __shared__ float mask_s[128], m2_s[128], v_s[128];
    __shared__ float obuf[32][132];
    const int t = threadIdx.x;
    const int i = t >> 4;   // h-group 0..31
    const int j = t & 15;   // k-group 0..15

    float covreg[4][8];
#pragma unroll
    for (int hh = 0; hh < 4; ++hh) {
        const float* cr = cov + (long)(i * 4 + hh) * 128 + j * 8;
        float4 c0 = *(const float4*)cr;
        float4 c1 = *(const float4*)(cr + 4);
        covreg[hh][0] = LOG2E * c0.x; covreg[hh][1] = LOG2E * c0.y;
        covreg[hh][2] = LOG2E * c0.z; covreg[hh][3] = LOG2E * c0.w;
        covreg[hh][4] = LOG2E * c1.x; covreg[hh][5] = LOG2E * c1.y;
        covreg[hh][6] = LOG2E * c1.z; covreg[hh][7] = LOG2E * c1.w;
    }
    float rmax_own = 0.f, rmin_own = 0.f, bias_own = 0.f;
    if (t < 128) {
        rmax_own = rmm[t];
        rmin_own = rmm[128 + t];
        bias_own = bias[t];
    }

    for (int b = blockIdx.x; b < B; b += gridDim.x) {
        if (t < 128) {
            float val = vm[(long)(2 * b) * 128 + t];
            float mk  = vm[(long)(2 * b + 1) * 128 + t];
            v_s[t] = val;
            mask_s[t] = mk;
            m2_s[t] = mk * (mk >= 0.f ? rmax_own : rmin_own);
        }
        __syncthreads();

        float op[8] = {0.f, 0.f, 0.f, 0.f, 0.f, 0.f, 0.f, 0.f};
#pragma unroll
        for (int hh = 0; hh < 4; ++hh) {
            float mh = mask_s[i * 4 + hh];
            float mm = m2_s[i * 4 + hh];
            float p[8];
            float lsum = 0.f;
#pragma unroll
            for (int kk = 0; kk < 8; ++kk) {
                float e = __builtin_amdgcn_exp2f(fmaf(mh, covreg[hh][kk], -mm));
                p[kk] = e;
                lsum += e;
            }
            // butterfly sum over the 16-lane j-group: all lanes get full l[h]
            lsum += __shfl_xor(lsum, 1, 16);
            lsum += __shfl_xor(lsum, 2, 16);
            lsum += __shfl_xor(lsum, 4, 16);
            lsum += __shfl_xor(lsum, 8, 16);
            float w = v_s[i * 4 + hh] * __builtin_amdgcn_rcpf(lsum);
#pragma unroll
            for (int kk = 0; kk < 8; ++kk) op[kk] = fmaf(w, p[kk], op[kk]);
        }
        *(float4*)&obuf[i][j * 8]     = make_float4(op[0], op[1], op[2], op[3]);
        *(float4*)&obuf[i][j * 8 + 4] = make_float4(op[4], op[5], op[6], op[7]);
        __syncthreads();

        if (t < 128) {
            float o = 0.f;
#pragma unroll
            for (int ii = 0; ii < 32; ++ii) o += obuf[ii][t];
            out[(long)b * 128 + t] = o + bias_own;
        }
        __syncthreads();
    }
}

extern "C" void kernel_launch(void* const* d_in, const int* in_sizes, int n_in,
                              void* d_out, int out_size, void* d_ws, size_t ws_size,
                              hipStream_t stream) {
    const float* x    = (const float*)d_in[0];
    const float* W    = (const float*)d_in[1];
    const float* cov  = (const float*)d_in[2];
    const float* bias = (const float*)d_in[3];
    float* out = (float*)d_out;

    const int B = in_sizes[0] / (2 * 1024);   // 16384

    float* vm  = (float*)d_ws;                          // [2B][128] fp32
    short* wbf = (short*)(vm + (size_t)2 * B * 128);    // [128*1024] bf16, frag order
    float* rmm = (float*)(wbf + 128 * 1024);            // [256]

    prep_kernel<<<192, 256, 0, stream>>>(W, cov, wbf, rmm);

    const int rows = 2 * B;                   // 32768
    const int blocks = rows / 64;             // 16 rows/wave, 4 waves/block -> 512
    proj_kernel<<<blocks, 256, 0, stream>>>(x, wbf, vm);

    combine_kernel<<<2048, 512, 0, stream>>>(vm, cov, bias, rmm, out, B);
}